// Round 5
// baseline (117.923 us; speedup 1.0000x reference)
//
#include <hip/hip_runtime.h>

typedef __attribute__((ext_vector_type(4))) float  f32x4;
typedef __attribute__((ext_vector_type(8))) __bf16 bf16x8;
typedef __attribute__((ext_vector_type(4))) __bf16 bf16x4;

#define MFMA16(a, b, c) __builtin_amdgcn_mfma_f32_16x16x32_bf16((a), (b), (c), 0, 0, 0)

// Pipelined persistent-8: one block per batch b, looping h=0..7.
// Global loads for head p+1 issue BEFORE compute of head p (async-stage split);
// single LDS buffer, 2 barriers/iter. LDS 14.8 KB.
__global__ __launch_bounds__(256, 5)
void mha_fused(const float* __restrict__ qg, const float* __restrict__ kg,
               const float* __restrict__ vg, const unsigned char* __restrict__ maskg,
               const float* __restrict__ gammag, const float* __restrict__ biasg,
               float* __restrict__ outg)
{
    const int b = blockIdx.x;            // 2048 blocks; block = one batch, all 8 heads
    const int t = threadIdx.x;

    __shared__ __bf16 sKh[64][40];       // K^T hi [j][d-slot], 16B-slot XOR swizzle
    __shared__ __bf16 sKl[64][40];       // K^T lo
    __shared__ __bf16 sV [32][72];       // V bf16 [d][j]

    const size_t base = (size_t)b * 8 * 2048;
    const unsigned char* mbp = maskg + (size_t)b * 4096;

    const int li = t & 15;
    const int hi = (t >> 4) & 3;
    const int w  = t >> 6;               // wave id: owns query cols i = w*16..+15
    const int i  = w * 16 + li;
    const int jK = t & 63;               // K-stage row; wave w stages d-slab w*8..w*8+7
    const int slotW = (w ^ ((jK >> 3) & 3)) * 8;
    const int vd = t >> 3, vj = (t & 7) * 8;

    // mask rows for my i — identical for all 8 heads; load once per block
    unsigned int mw[4];
    #pragma unroll
    for (int jt = 0; jt < 4; ++jt)
        mw[jt] = *(const unsigned int*)&mbp[i * 64 + jt * 16 + hi * 4];

    // ---------------- prologue: load + stage head 0 ----------------
    float kv[8], qv[8];
    f32x4 v0x, v1x;
    {
        const float* kb = kg + base;
        #pragma unroll
        for (int e = 0; e < 8; ++e) kv[e] = kb[(w * 8 + e) * 64 + jK];
        const float* vb = vg + base;
        v0x = *(const f32x4*)(vb + t * 8);
        v1x = *(const f32x4*)(vb + t * 8 + 4);
        const float* qb = qg + base;
        #pragma unroll
        for (int e = 0; e < 8; ++e) qv[e] = qb[(hi * 8 + e) * 64 + i];
    }
    bf16x8 qh, ql;
    {
        bf16x8 h8, l8;
        #pragma unroll
        for (int e = 0; e < 8; ++e) {
            const __bf16 hh = (__bf16)kv[e];
            h8[e] = hh; l8[e] = (__bf16)(kv[e] - (float)hh);
        }
        *(bf16x8*)&sKh[jK][slotW] = h8;
        *(bf16x8*)&sKl[jK][slotW] = l8;
        bf16x8 vv = {(__bf16)v0x[0], (__bf16)v0x[1], (__bf16)v0x[2], (__bf16)v0x[3],
                     (__bf16)v1x[0], (__bf16)v1x[1], (__bf16)v1x[2], (__bf16)v1x[3]};
        *(bf16x8*)&sV[vd][vj] = vv;
        #pragma unroll
        for (int e = 0; e < 8; ++e) {
            const __bf16 hh = (__bf16)qv[e];
            qh[e] = hh; ql[e] = (__bf16)(qv[e] - (float)hh);
        }
    }
    __syncthreads();

    #pragma unroll 1
    for (int p = 0; p < 8; ++p) {
        // ---- prefetch head p+1 into registers (latency hides under compute) ----
        float kvn[8], qvn[8];
        f32x4 v0n, v1n;
        const bool pre = (p < 7);
        if (pre) {
            const size_t nb = base + (size_t)(p + 1) * 2048;
            const float* kb = kg + nb;
            #pragma unroll
            for (int e = 0; e < 8; ++e) kvn[e] = kb[(w * 8 + e) * 64 + jK];
            const float* vb = vg + nb;
            v0n = *(const f32x4*)(vb + t * 8);
            v1n = *(const f32x4*)(vb + t * 8 + 4);
            const float* qb = qg + nb;
            #pragma unroll
            for (int e = 0; e < 8; ++e) qvn[e] = qb[(hi * 8 + e) * 64 + i];
        }

        // ---- compute head p: S^T = K^T Q (split-bf16), softmax*sigmoid, PV ----
        const float ga = gammag[p], be = biasg[p];
        float s[16];
        #pragma unroll
        for (int jt = 0; jt < 4; ++jt) {
            const int j = jt * 16 + li;
            const int slot = (hi ^ ((j >> 3) & 3)) * 8;
            bf16x8 ah = *(bf16x8*)&sKh[j][slot];
            bf16x8 al = *(bf16x8*)&sKl[j][slot];
            f32x4 c = {0.f, 0.f, 0.f, 0.f};
            c = MFMA16(al, qh, c);   // lo*hi
            c = MFMA16(ah, ql, c);   // hi*lo
            c = MFMA16(ah, qh, c);   // hi*hi
            #pragma unroll
            for (int r = 0; r < 4; ++r) {
                float x = c[r] * ga + be;
                if ((mw[jt] >> (8 * r)) & 0xffu) x = -1.0e9f;
                s[jt * 4 + r] = x;
            }
        }
        float m = s[0];
        #pragma unroll
        for (int e = 1; e < 16; ++e) m = fmaxf(m, s[e]);
        m = fmaxf(m, __shfl_xor(m, 16));
        m = fmaxf(m, __shfl_xor(m, 32));
        const float em = __expf(-m);   // sigmoid(s) = p/(p+em); all-masked -> gate 0
        float sum = 0.f;
        #pragma unroll
        for (int e = 0; e < 16; ++e) { s[e] = __expf(s[e] - m); sum += s[e]; }
        sum += __shfl_xor(sum, 16);
        sum += __shfl_xor(sum, 32);
        const float inv = 1.0f / sum;

        bf16x4 wv[4];
        #pragma unroll
        for (int jt = 0; jt < 4; ++jt) {
            #pragma unroll
            for (int r = 0; r < 4; ++r) {
                const float pp = s[jt * 4 + r];
                wv[jt][r] = (__bf16)(pp * inv * __fdividef(pp, pp + em));
            }
        }

        f32x4 o0 = {0.f, 0.f, 0.f, 0.f}, o1 = {0.f, 0.f, 0.f, 0.f};
        #pragma unroll
        for (int kt = 0; kt < 2; ++kt) {
            bf16x4 wlo = wv[2 * kt], whi2 = wv[2 * kt + 1];
            bf16x8 wb = {wlo[0], wlo[1], wlo[2], wlo[3], whi2[0], whi2[1], whi2[2], whi2[3]};
            const int c0 = kt * 32 + hi * 4, c1 = kt * 32 + 16 + hi * 4;
            bf16x4 a0l = *(const bf16x4*)&sV[li][c0];
            bf16x4 a0h = *(const bf16x4*)&sV[li][c1];
            bf16x8 va = {a0l[0], a0l[1], a0l[2], a0l[3], a0h[0], a0h[1], a0h[2], a0h[3]};
            bf16x4 a1l = *(const bf16x4*)&sV[16 + li][c0];
            bf16x4 a1h = *(const bf16x4*)&sV[16 + li][c1];
            bf16x8 vc = {a1l[0], a1l[1], a1l[2], a1l[3], a1h[0], a1h[1], a1h[2], a1h[3]};
            o0 = MFMA16(va, wb, o0);
            o1 = MFMA16(vc, wb, o1);
        }
        float* ob = outg + base + (size_t)p * 2048;
        #pragma unroll
        for (int r = 0; r < 4; ++r) {
            ob[(hi * 4 + r) * 64 + i]      = o0[r];
            ob[(16 + hi * 4 + r) * 64 + i] = o1[r];
        }

        // ---- stage head p+1 (loads already in flight; convert + LDS write) ----
        if (pre) {
            __syncthreads();   // (A) all waves done reading LDS for head p
            bf16x8 h8, l8;
            #pragma unroll
            for (int e = 0; e < 8; ++e) {
                const __bf16 hh = (__bf16)kvn[e];
                h8[e] = hh; l8[e] = (__bf16)(kvn[e] - (float)hh);
            }
            *(bf16x8*)&sKh[jK][slotW] = h8;
            *(bf16x8*)&sKl[jK][slotW] = l8;
            bf16x8 vv = {(__bf16)v0n[0], (__bf16)v0n[1], (__bf16)v0n[2], (__bf16)v0n[3],
                         (__bf16)v1n[0], (__bf16)v1n[1], (__bf16)v1n[2], (__bf16)v1n[3]};
            *(bf16x8*)&sV[vd][vj] = vv;
            #pragma unroll
            for (int e = 0; e < 8; ++e) {
                const __bf16 hh = (__bf16)qvn[e];
                qh[e] = hh; ql[e] = (__bf16)(qvn[e] - (float)hh);
            }
            __syncthreads();   // (B) staged data visible before compute of head p+1
        }
    }
}

extern "C" void kernel_launch(void* const* d_in, const int* in_sizes, int n_in,
                              void* d_out, int out_size, void* d_ws, size_t ws_size,
                              hipStream_t stream)
{
    const float* q = (const float*)d_in[0];
    const float* k = (const float*)d_in[1];
    const float* v = (const float*)d_in[2];
    const unsigned char* mask = (const unsigned char*)d_in[3];
    const float* gamma = (const float*)d_in[4];
    const float* bias  = (const float*)d_in[5];
    float* out = (float*)d_out;

    const int num_bh = in_sizes[0] / 2048;   // bs*h = 16384
    dim3 grid(num_bh >> 3), block(256);      // one block per batch b
    hipLaunchKernelGGL(mha_fused, grid, block, 0, stream,
                       q, k, v, mask, gamma, bias, out);
}

// Round 6
// 105.002 us; speedup vs baseline: 1.1230x; 1.1230x over previous
//
#include <hip/hip_runtime.h>

typedef __attribute__((ext_vector_type(4))) float  f32x4;
typedef __attribute__((ext_vector_type(8))) __bf16 bf16x8;
typedef __attribute__((ext_vector_type(4))) __bf16 bf16x4;

#define MFMA16(a, b, c) __builtin_amdgcn_mfma_f32_16x16x32_bf16((a), (b), (c), 0, 0, 0)

// One block per (b,h), natural grid order (dense streaming frontier).
// All global loads issued upfront (consumption order), pinned by sched_barrier.
// LDS 14.8 KB; launch_bounds(256,4) = R1's proven occupancy regime.
__global__ __launch_bounds__(256, 4)
void mha_fused(const float* __restrict__ qg, const float* __restrict__ kg,
               const float* __restrict__ vg, const unsigned char* __restrict__ maskg,
               const float* __restrict__ gammag, const float* __restrict__ biasg,
               float* __restrict__ outg)
{
    const int bh = blockIdx.x;
    const int b  = bh >> 3;
    const int h  = bh & 7;
    const int t  = threadIdx.x;

    __shared__ __bf16 sKh[64][40];   // K^T hi [j][d-slot], 16B-slot XOR swizzle
    __shared__ __bf16 sKl[64][40];   // K^T lo
    __shared__ __bf16 sV [32][72];   // V bf16 [d][j]

    const float* qb = qg + (size_t)bh * 2048;
    const float* kb = kg + (size_t)bh * 2048;
    const float* vb = vg + (size_t)bh * 2048;
    const unsigned char* mbp = maskg + (size_t)b * 4096;  // mask broadcast over h
    float* ob = outg + (size_t)bh * 2048;

    const int w  = t >> 6;          // wave id: owns query cols i = w*16..w*16+15
    const int li = t & 15;
    const int hi = (t >> 4) & 3;
    const int i  = w * 16 + li;

    // ---------- issue ALL global loads upfront, in consumption order ----------
    // K (consumed first: convert+stage)
    const int jK  = t & 63, sel = t >> 6;
    float a[8];
    #pragma unroll
    for (int e = 0; e < 8; ++e) a[e] = kb[(sel * 8 + e) * 64 + jK];
    // V (consumed second)
    f32x4 x0 = *(const f32x4*)(vb + t * 8);
    f32x4 x1 = *(const f32x4*)(vb + t * 8 + 4);
    // Q (consumed third)
    float qv[8];
    #pragma unroll
    for (int e = 0; e < 8; ++e) qv[e] = qb[(hi * 8 + e) * 64 + i];
    // mask (consumed last, after the barrier)
    unsigned int mw[4];
    #pragma unroll
    for (int jt = 0; jt < 4; ++jt)
        mw[jt] = *(const unsigned int*)&mbp[i * 64 + jt * 16 + hi * 4];
    __builtin_amdgcn_sched_barrier(0);   // pin: no sinking of the loads below

    // ---------- convert + stage (waits resolve in issue order) ----------
    {
        bf16x8 h8, l8;
        #pragma unroll
        for (int e = 0; e < 8; ++e) {
            const __bf16 hh = (__bf16)a[e];
            h8[e] = hh;
            l8[e] = (__bf16)(a[e] - (float)hh);
        }
        const int slot = sel ^ ((jK >> 3) & 3);
        *(bf16x8*)&sKh[jK][slot * 8] = h8;
        *(bf16x8*)&sKl[jK][slot * 8] = l8;
    }
    {
        const int d = t >> 3, j0 = (t & 7) * 8;
        bf16x8 vv = {(__bf16)x0[0], (__bf16)x0[1], (__bf16)x0[2], (__bf16)x0[3],
                     (__bf16)x1[0], (__bf16)x1[1], (__bf16)x1[2], (__bf16)x1[3]};
        *(bf16x8*)&sV[d][j0] = vv;
    }
    bf16x8 qh, ql;
    #pragma unroll
    for (int e = 0; e < 8; ++e) {
        const __bf16 hh = (__bf16)qv[e];
        qh[e] = hh;
        ql[e] = (__bf16)(qv[e] - (float)hh);
    }
    __syncthreads();

    // ---------- S^T[j][i] = sum_d K^T[j][d] * Q[d][i] (split-bf16) ----------
    const float ga = gammag[h], be = biasg[h];
    float s[16];
    #pragma unroll
    for (int jt = 0; jt < 4; ++jt) {
        const int j = jt * 16 + li;
        const int slot = hi ^ ((j >> 3) & 3);
        bf16x8 ah = *(bf16x8*)&sKh[j][slot * 8];
        bf16x8 al = *(bf16x8*)&sKl[j][slot * 8];
        f32x4 c = {0.f, 0.f, 0.f, 0.f};
        c = MFMA16(al, qh, c);   // lo*hi
        c = MFMA16(ah, ql, c);   // hi*lo
        c = MFMA16(ah, qh, c);   // hi*hi
        #pragma unroll
        for (int r = 0; r < 4; ++r) {
            float x = c[r] * ga + be;
            if ((mw[jt] >> (8 * r)) & 0xffu) x = -1.0e9f;
            s[jt * 4 + r] = x;
        }
    }

    // ---------- softmax over j: 16 in-lane + 2 shuffles (4 hi-lanes share i) ----------
    float m = s[0];
    #pragma unroll
    for (int e = 1; e < 16; ++e) m = fmaxf(m, s[e]);
    m = fmaxf(m, __shfl_xor(m, 16));
    m = fmaxf(m, __shfl_xor(m, 32));
    const float em = __expf(-m);   // sigmoid(s) = p/(p+em); all-masked -> em=inf -> gate 0
    float sum = 0.f;
    #pragma unroll
    for (int e = 0; e < 16; ++e) { s[e] = __expf(s[e] - m); sum += s[e]; }
    sum += __shfl_xor(sum, 16);
    sum += __shfl_xor(sum, 32);
    const float inv = 1.0f / sum;

    // ---------- gate: w = (p*inv) * (p/(p+em)); in-register PV B-fragments ----------
    bf16x4 wv[4];
    #pragma unroll
    for (int jt = 0; jt < 4; ++jt) {
        #pragma unroll
        for (int r = 0; r < 4; ++r) {
            const float p = s[jt * 4 + r];
            wv[jt][r] = (__bf16)(p * inv * __fdividef(p, p + em));
        }
    }

    // ---------- PV: out[d][i] = sum_j V[d][j] * W[i][j]; wv[] IS the B-frag ----------
    f32x4 o0 = {0.f, 0.f, 0.f, 0.f};
    f32x4 o1 = {0.f, 0.f, 0.f, 0.f};
    #pragma unroll
    for (int kt = 0; kt < 2; ++kt) {
        bf16x4 wlo = wv[2 * kt], whi2 = wv[2 * kt + 1];
        bf16x8 wb = {wlo[0], wlo[1], wlo[2], wlo[3], whi2[0], whi2[1], whi2[2], whi2[3]};
        const int c0 = kt * 32 + hi * 4;
        const int c1 = kt * 32 + 16 + hi * 4;
        bf16x4 a0l = *(const bf16x4*)&sV[li][c0];
        bf16x4 a0h = *(const bf16x4*)&sV[li][c1];
        bf16x8 va = {a0l[0], a0l[1], a0l[2], a0l[3], a0h[0], a0h[1], a0h[2], a0h[3]};
        bf16x4 a1l = *(const bf16x4*)&sV[16 + li][c0];
        bf16x4 a1h = *(const bf16x4*)&sV[16 + li][c1];
        bf16x8 vc = {a1l[0], a1l[1], a1l[2], a1l[3], a1h[0], a1h[1], a1h[2], a1h[3]};
        o0 = MFMA16(va, wb, o0);
        o1 = MFMA16(vc, wb, o1);
    }
    #pragma unroll
    for (int r = 0; r < 4; ++r) {
        ob[(hi * 4 + r) * 64 + i]      = o0[r];
        ob[(16 + hi * 4 + r) * 64 + i] = o1[r];
    }
}

extern "C" void kernel_launch(void* const* d_in, const int* in_sizes, int n_in,
                              void* d_out, int out_size, void* d_ws, size_t ws_size,
                              hipStream_t stream)
{
    const float* q = (const float*)d_in[0];
    const float* k = (const float*)d_in[1];
    const float* v = (const float*)d_in[2];
    const unsigned char* mask = (const unsigned char*)d_in[3];
    const float* gamma = (const float*)d_in[4];
    const float* bias  = (const float*)d_in[5];
    float* out = (float*)d_out;

    const int num_bh = in_sizes[0] / 2048;   // bs*h = 16384
    dim3 grid(num_bh), block(256);
    hipLaunchKernelGGL(mha_fused, grid, block, 0, stream,
                       q, k, v, mask, gamma, bias, out);
}